// Round 11
// baseline (1213.465 us; speedup 1.0000x reference)
//
#include <hip/hip_runtime.h>
#include <math.h>

#define BOX   256
#define NPTS  50000
#define LATD  10
#define NEUR  32
#define NLAY  3
#define BATCH 16

#define MTPB  256
#define MBLKX ((NPTS + MTPB - 1)/MTPB)     // 196 point-tiles per image
#define NTILES (MBLKX*BATCH)               // 3136

#define CELLS_X 64                          // 4x4-px cells
#define CELLS   (CELLS_X*CELLS_X)           // 4096
#define PREF_STRIDE 4104
#define CHUNK   128
#define WCAP    4608

#define IMG_ELEMS (BATCH*BOX*BOX)
#define OFF_IMG2  (IMG_ELEMS)
#define OFF_PROJ  (2*IMG_ELEMS)
#define OFF_POS   (OFF_PROJ + BATCH*NPTS*2)
#define OFF_RES   (OFF_POS  + BATCH*NPTS*3)

// ws ints: counts[16*4096] | n_work[16] | prefix[16*4104] | work[16*4608] | aux[16*50000]
// then (16B aligned): recs float4[16*50000]. Barrier counter lives in the spare
// padding int of image-0's prefix row (PREF_STRIDE=4104 > CELLS+1=4097).
#define WS_COUNTS 0
#define WS_NWORK  (BATCH*CELLS)
#define WS_PREFIX (WS_NWORK + BATCH)
#define WS_WORK   (WS_PREFIX + BATCH*PREF_STRIDE)
#define WS_AUX    (WS_WORK + BATCH*WCAP)
#define WS_INTS   (WS_AUX + BATCH*NPTS)
#define BAR_IDX   (WS_PREFIX + CELLS + 1)

// LDS: mlp tiles need 20608 B (4 x [64][HSTRH] fp16 + 32 f32); scan needs 16428 B.
#define HSTRH 40
#define LDS_BYTES (4*64*HSTRH*2 + NEUR*4)

typedef _Float16 f16x8 __attribute__((ext_vector_type(8)));
typedef _Float16 f16x4 __attribute__((ext_vector_type(4)));
typedef float    f32x4 __attribute__((ext_vector_type(4)));

#if __has_builtin(__builtin_amdgcn_exp2f)
#define EXP2R(x) __builtin_amdgcn_exp2f(x)
#else
#define EXP2R(x) exp2f(x)
#endif

__device__ __forceinline__ float fast_tanh(float x) {
    return 1.0f - 2.0f / (__expf(2.0f * x) + 1.0f);
}

// Grid barrier (monotonic counter). Used ONLY under hipLaunchCooperativeKernel,
// which validates grid <= co-resident capacity at launch (fails loudly, no hang).
// release-add / acquire-spin at agent scope = documented cross-XCD mitigation.
__device__ __forceinline__ void gbar(int* bar, int target) {
    __syncthreads();
    if (threadIdx.x == 0) {
        __threadfence();
        __hip_atomic_fetch_add(bar, 1, __ATOMIC_RELEASE, __HIP_MEMORY_SCOPE_AGENT);
        while (__hip_atomic_load(bar, __ATOMIC_ACQUIRE, __HIP_MEMORY_SCOPE_AGENT) < target)
            __builtin_amdgcn_s_sleep(32);
        __threadfence();
    }
    __syncthreads();
}

// ================= shared phase bodies =================

// P1 body: fused MLP + binning for one 256-point tile. (R9-proven.)
__device__ __forceinline__ void do_mlp_tile(
    const int tile, const int tid, unsigned char* s_raw, const int dd,
    const float* __restrict__ z, const float* __restrict__ r,
    const float* __restrict__ pos_param,
    const float* __restrict__ lin0_w, const float* __restrict__ deform_w,
    const float* __restrict__ deform_b, const float* __restrict__ lin1a_w,
    const float* __restrict__ lin1b_w,
    float* __restrict__ out, int* __restrict__ counts, int* __restrict__ aux)
{
    _Float16* s_h   = (_Float16*)s_raw;
    float*    s_z   = (float*)(s_raw + 4*64*HSTRH*2);
    int*      s_cnt = (int*)s_raw;          // aliases tiles; used post-reads only
    const int wave  = tid >> 6;
    const int lane  = tid & 63;
    const int cfrag = lane & 15;            // A row / B col / D col
    const int rq    = lane >> 4;
    const int k0    = rq * 8;
    _Float16* __restrict__ s_hw = s_h + wave*64*HSTRH;

    const int b  = tile / MBLKX;
    const int tx = tile - b*MBLKX;

    if (tid < NEUR) {
        float acc = 0.f;
        #pragma unroll
        for (int j = 0; j < LATD-1; j++)
            acc = fmaf(lin0_w[tid*12 + 3 + j], z[b*LATD + j], acc);
        s_z[tid] = acc;
    }
    __syncthreads();    // also protects s_cnt->s_hw reuse across consecutive tiles

    const int n  = tx*MTPB + tid;
    const bool v0 = (n < NPTS);
    const int m0 = v0 ? n : (NPTS-1);

    const float p0w = pos_param[m0*3+0], p1w = pos_param[m0*3+1], p2w = pos_param[m0*3+2];
    float res0 = 0.f, res1 = 0.f, res2 = 0.f;

    if (dd > 0) {
        f16x8 bfrag[NLAY][2];
        float bias_c[NLAY][2];
        #pragma unroll
        for (int l = 0; l < NLAY; ++l) {
            #pragma unroll
            for (int nt = 0; nt < 2; ++nt) {
                const int c = cfrag + 16*nt;
                const float* wp = deform_w + l*NEUR*NEUR + c*NEUR + k0;
                const f32x4 w0 = *(const f32x4*)wp;
                const f32x4 w1 = *(const f32x4*)(wp + 4);
                f16x8 bv;
                bv[0]=(_Float16)w0[0]; bv[1]=(_Float16)w0[1];
                bv[2]=(_Float16)w0[2]; bv[3]=(_Float16)w0[3];
                bv[4]=(_Float16)w1[0]; bv[5]=(_Float16)w1[1];
                bv[6]=(_Float16)w1[2]; bv[7]=(_Float16)w1[3];
                bfrag[l][nt]  = bv;
                bias_c[l][nt] = deform_b[l*NEUR + c];
            }
        }

        #pragma unroll
        for (int o4 = 0; o4 < 8; ++o4) {
            f16x4 h4;
            #pragma unroll
            for (int jj = 0; jj < 4; ++jj) {
                const int o = o4*4 + jj;
                h4[jj] = (_Float16)fmaf(lin0_w[o*12+0], p0w,
                                   fmaf(lin0_w[o*12+1], p1w,
                                   fmaf(lin0_w[o*12+2], p2w, s_z[o])));
            }
            *(f16x4*)&s_hw[lane*HSTRH + o4*4] = h4;
        }
        __syncthreads();

        float rs0[4][4], rs1[4][4];
        #pragma unroll
        for (int mt = 0; mt < 4; ++mt) {
            #pragma unroll
            for (int rr = 0; rr < 4; ++rr) {
                const int row = 16*mt + 4*rq + rr;
                rs0[mt][rr] = (float)s_hw[row*HSTRH + cfrag];
                rs1[mt][rr] = (float)s_hw[row*HSTRH + cfrag + 16];
            }
        }

        const f32x4 zc = {0.f, 0.f, 0.f, 0.f};
        #pragma unroll
        for (int l = 0; l < NLAY; ++l) {
            f16x8 af[4];
            #pragma unroll
            for (int mt = 0; mt < 4; ++mt)
                af[mt] = *(const f16x8*)&s_hw[(16*mt + cfrag)*HSTRH + k0];
            f32x4 ac0[4], ac1[4];
            #pragma unroll
            for (int mt = 0; mt < 4; ++mt) {
                ac0[mt] = __builtin_amdgcn_mfma_f32_16x16x32_f16(af[mt], bfrag[l][0], zc, 0, 0, 0);
                ac1[mt] = __builtin_amdgcn_mfma_f32_16x16x32_f16(af[mt], bfrag[l][1], zc, 0, 0, 0);
            }
            __syncthreads();
            const float b0l = bias_c[l][0], b1l = bias_c[l][1];
            #pragma unroll
            for (int mt = 0; mt < 4; ++mt) {
                #pragma unroll
                for (int rr = 0; rr < 4; ++rr) {
                    const int row = 16*mt + 4*rq + rr;
                    const float h0n = fmaxf(ac0[mt][rr] + b0l, 0.f) + rs0[mt][rr];
                    const float h1n = fmaxf(ac1[mt][rr] + b1l, 0.f) + rs1[mt][rr];
                    rs0[mt][rr] = h0n;
                    rs1[mt][rr] = h1n;
                    s_hw[row*HSTRH + cfrag]      = (_Float16)h0n;
                    s_hw[row*HSTRH + cfrag + 16] = (_Float16)h1n;
                }
            }
            __syncthreads();
        }

        float t0 = 0.f, t1 = 0.f, t2 = 0.f;
        #pragma unroll
        for (int ch = 0; ch < 4; ++ch) {
            const f16x8 hv = *(const f16x8*)&s_hw[lane*HSTRH + ch*8];
            #pragma unroll
            for (int jj = 0; jj < 8; ++jj) {
                const int j = ch*8 + jj;
                const float hf = (float)hv[jj];
                t0 = fmaf(lin1a_w[0*NEUR + j], hf, t0);
                t1 = fmaf(lin1a_w[1*NEUR + j], hf, t1);
                t2 = fmaf(lin1a_w[2*NEUR + j], hf, t2);
            }
        }
        t0 = fast_tanh(t0); t1 = fast_tanh(t1); t2 = fast_tanh(t2);
        res0 = fmaf(t0, lin1b_w[0], fmaf(t1, lin1b_w[1], t2*lin1b_w[2]));
        res1 = fmaf(t0, lin1b_w[3], fmaf(t1, lin1b_w[4], t2*lin1b_w[5]));
        res2 = fmaf(t0, lin1b_w[6], fmaf(t1, lin1b_w[7], t2*lin1b_w[8]));
    }

    const float r00 = r[b*9+0], r01 = r[b*9+1];
    const float r10 = r[b*9+3], r11 = r[b*9+4];
    const float r20 = r[b*9+6], r21 = r[b*9+7];

    int cell = 0;
    if (v0) {
        const float pos0 = p0w + res0, pos1 = p1w + res1, pos2 = p2w + res2;
        const float pj0 = fmaf(pos0, r00, fmaf(pos1, r10, pos2*r20));
        const float pj1 = fmaf(pos0, r01, fmaf(pos1, r11, pos2*r21));
        const long long bn = (long long)b*NPTS + n;
        out[OFF_PROJ + bn*2 + 0] = pj0;  out[OFF_PROJ + bn*2 + 1] = pj1;
        out[OFF_POS  + bn*3 + 0] = pos0; out[OFF_POS  + bn*3 + 1] = pos1;
        out[OFF_POS  + bn*3 + 2] = pos2;
        out[OFF_RES  + bn*3 + 0] = res0; out[OFF_RES + bn*3 + 1] = res1;
        out[OFF_RES  + bn*3 + 2] = res2;
        const float px0 = (pj0 + 0.5f) * (float)(BOX-1);
        const float px1 = (pj1 + 0.5f) * (float)(BOX-1);
        const int c0 = (int)fminf(fmaxf(floorf(px0 + 0.5f), 0.f), 255.f);
        const int c1 = (int)fminf(fmaxf(floorf(px1 + 0.5f), 0.f), 255.f);
        cell = (c0>>2)*CELLS_X + (c1>>2);
    }

    __syncthreads();
    for (int i = tid; i < CELLS; i += MTPB) s_cnt[i] = 0;
    __syncthreads();
    int rank = 0;
    if (v0) rank = atomicAdd(&s_cnt[cell], 1);
    __syncthreads();
    for (int c = tid; c < CELLS; c += MTPB) {
        const int cnt = s_cnt[c];
        if (cnt > 0) s_cnt[c] = atomicAdd(&counts[b*CELLS + c], cnt);
    }
    __syncthreads();
    if (v0) aux[b*NPTS + n] = (cell << 16) | (s_cnt[cell] + rank);
}

// P2 body: per-image scan (256 thr, 16 cells/thr) + work build + idx scatter.
__device__ __forceinline__ void do_scan_img(
    const int img, const int tid, unsigned char* s_raw,
    const int* __restrict__ counts, int* __restrict__ prefix,
    int* __restrict__ n_work, int* __restrict__ work,
    const int* __restrict__ aux, int* __restrict__ recs_i)
{
    int* sprefix = (int*)s_raw;            // 4097 ints
    int* swsum   = sprefix + 4100;         // 4 ints
    int* snw     = sprefix + 4106;
    const int lane = tid & 63, wid = tid >> 6;
    if (tid == 0) *snw = 0;

    int c[16];
    const int4* cp = (const int4*)(counts + img*CELLS) + tid*4;
    #pragma unroll
    for (int q = 0; q < 4; ++q) {
        const int4 v = cp[q];
        c[q*4+0]=v.x; c[q*4+1]=v.y; c[q*4+2]=v.z; c[q*4+3]=v.w;
    }
    int pres[16]; int run = 0;
    #pragma unroll
    for (int i = 0; i < 16; ++i) { pres[i] = run; run += c[i]; }

    int sc = run;
    #pragma unroll
    for (int off = 1; off < 64; off <<= 1) {
        const int u = __shfl_up(sc, off, 64);
        if (lane >= off) sc += u;
    }
    if (lane == 63) swsum[wid] = sc;
    __syncthreads();
    int woff = 0;
    #pragma unroll
    for (int w = 0; w < 3; ++w) if (w < wid) woff += swsum[w];
    const int base = woff + sc - run;

    int* gpre = prefix + img*PREF_STRIDE;
    #pragma unroll
    for (int i = 0; i < 16; ++i) {
        const int pv = base + pres[i];
        sprefix[tid*16 + i] = pv;
        gpre[tid*16 + i]    = pv;
    }
    if (tid == 255) { const int grand = woff + sc; sprefix[CELLS] = grand; gpre[CELLS] = grand; }
    __syncthreads();

    #pragma unroll
    for (int i = 0; i < 16; ++i) {
        const int cnt = c[i];
        if (cnt > 0) {
            const int cell = tid*16 + i;
            const int nch = (cnt + CHUNK - 1) >> 7;
            const int wb = atomicAdd(snw, nch);
            for (int k = 0; k < nch; ++k) work[img*WCAP + wb + k] = (cell << 9) | k;
        }
    }
    __syncthreads();
    if (tid == 0) n_work[img] = *snw;

    for (int n = tid; n < NPTS; n += MTPB) {
        const int av = aux[img*NPTS + n];
        const int dst = sprefix[av >> 16] + (av & 0xFFFF);
        recs_i[((long long)img*NPTS + dst)*4 + 3] = n;
    }
}

// P3 body: coalesced record fill from scattered reads (one element).
__device__ __forceinline__ void do_fill_elem(
    const int i, const float* __restrict__ z, const float* __restrict__ amp,
    const float* __restrict__ linamp_w, const float* __restrict__ linamp_b,
    const float* __restrict__ out, float4* __restrict__ recs)
{
    const int b = i / NPTS;
    const int n = ((const int*)recs)[(long long)i*4 + 3];
    const long long bn = (long long)b*NPTS + n;
    const float pj0 = out[OFF_PROJ + bn*2 + 0];
    const float pj1 = out[OFF_PROJ + bn*2 + 1];
    const float lo = fmaf(z[b*LATD + LATD-1], linamp_w[n], linamp_b[n]);
    const float a  = amp[0] / (1.0f + __expf(-lo));
    const float px0 = (pj0 + 0.5f) * (float)(BOX-1);
    const float px1 = (pj1 + 0.5f) * (float)(BOX-1);
    recs[i] = make_float4(px0, px1, a, floorf(px0 + 0.5f));
}

// P4 body: gather over the GLOBAL chunk list (all images jointly, balanced);
// dual-writes both output image copies (replaces the copy kernel).
__device__ __forceinline__ void do_gather(
    const int gw, const int GW, const int lane,
    const float4* __restrict__ recs, const int* __restrict__ prefix,
    const int* __restrict__ n_work, const int* __restrict__ work,
    float* __restrict__ out)
{
    const float Kc  = -0.32059884f;            // -log2(e)/(2*sig^2)
    const float K8  = 8.0f  * Kc;
    const float K16 = 16.0f * Kc;
    const float C32 = 0.00081582472f;          // 2^(32*Kc)

    // prefix over n_work[0..15]; all indices static (rule #20: no scratch)
    int nwoff[BATCH+1];
    nwoff[0] = 0;
    #pragma unroll
    for (int q = 0; q < BATCH; ++q) nwoff[q+1] = nwoff[q] + n_work[q];
    const int total = nwoff[BATCH];

    for (int g = gw; g < total; g += GW) {
        int b = 0, base = 0;
        #pragma unroll
        for (int q = 0; q < BATCH; ++q) {
            const bool geq = (g >= nwoff[q+1]);
            b    = geq ? q+1        : b;
            base = geq ? nwoff[q+1] : base;
        }
        const int it = g - base;

        const int* __restrict__ P = prefix + b*PREF_STRIDE;
        const float4* __restrict__ R = recs + (long long)b*NPTS;
        float* __restrict__ img  = out + (size_t)b*BOX*BOX;
        float* __restrict__ img2 = out + OFF_IMG2 + (size_t)b*BOX*BOX;

        const int wd   = __builtin_amdgcn_readfirstlane(work[b*WCAP + it]);
        const int cell = wd >> 9, kch = wd & 511;
        const int s = P[cell] + kch*CHUNK;
        const int e = min(P[cell+1], s + CHUNK);

        const int cy = cell >> 6, cx = cell & 63;
        const int col = lane & 15, r0 = lane >> 4;
        const int gx  = 4*cx - 4 + col;
        const int gy0 = 4*cy - 4 + r0;
        const float xf  = (float)gx;
        const float y0f = (float)gy0;
        const float frc = (float)(r0 + 4*cy);

        float a0 = 0.f, a1 = 0.f, a2 = 0.f;
        #pragma unroll 8
        for (int rr = s; rr < e; ++rr) {
            const float4 rc = R[rr];            // uniform addr -> s_load_dwordx4
            const float ry = rc.x, rx = rc.y, ra = rc.z, stf = rc.w;
            const float dx = xf - rx;
            const float dy = y0f - ry;
            const float d2 = fmaf(dy, dy, dx*dx);
            float gv = ra * EXP2R(d2 * Kc);
            gv = (fabsf(dx) <= 4.5f) ? gv : 0.f;
            const float u  = EXP2R(fminf(fmaf(dy, K8, K16), 60.f));
            const float uu = (u * u) * C32;
            const float g0m = (frc >= stf) ? gv : 0.f;
            const float u2m = (frc <= stf) ? uu : 0.f;
            a0 += g0m;
            a1 = fmaf(gv, u,   a1);
            a2 = fmaf(gv, u2m, a2);
        }

        if (gx >= 0 && gx < BOX) {
            if (a0 != 0.f && gy0 >= 0) {
                atomicAdd(&img [ gy0     *BOX + gx], a0);
                atomicAdd(&img2[ gy0     *BOX + gx], a0);
            }
            if (a1 != 0.f) {
                atomicAdd(&img [(gy0 + 4)*BOX + gx], a1);
                atomicAdd(&img2[(gy0 + 4)*BOX + gx], a1);
            }
            if (a2 != 0.f && gy0 + 8 < BOX) {
                atomicAdd(&img [(gy0 + 8)*BOX + gx], a2);
                atomicAdd(&img2[(gy0 + 8)*BOX + gx], a2);
            }
        }
    }
}

// ================= mega kernel (cooperative path) =================
__global__ __launch_bounds__(MTPB, 4) void mega(
    const float* __restrict__ z, const float* __restrict__ r,
    const float* __restrict__ pos_param, const float* __restrict__ amp,
    const float* __restrict__ lin0_w, const float* __restrict__ deform_w,
    const float* __restrict__ deform_b, const float* __restrict__ lin1a_w,
    const float* __restrict__ lin1b_w, const float* __restrict__ linamp_w,
    const float* __restrict__ linamp_b, const int* __restrict__ dflag,
    float* __restrict__ out, int* __restrict__ ws_i, float4* __restrict__ recs,
    const int G)
{
    __shared__ __align__(16) unsigned char s_raw[LDS_BYTES];

    int* counts = ws_i + WS_COUNTS;
    int* n_work = ws_i + WS_NWORK;
    int* prefix = ws_i + WS_PREFIX;
    int* work   = ws_i + WS_WORK;
    int* aux    = ws_i + WS_AUX;
    int* bar    = ws_i + BAR_IDX;

    const int blk  = blockIdx.x;
    const int tid  = threadIdx.x;
    const int gtid = blk*MTPB + tid;
    const int NT   = G*MTPB;
    const int dd   = *dflag;

    // P0: zero counts + BOTH image copies
    for (int i = gtid; i < (BATCH*CELLS)/4; i += NT)
        ((int4*)counts)[i] = make_int4(0, 0, 0, 0);
    for (int i = gtid; i < (2*IMG_ELEMS)/4; i += NT)
        ((float4*)out)[i] = make_float4(0.f, 0.f, 0.f, 0.f);

    gbar(bar, G*1);

    // P1: fused MLP + binning
    for (int tile = blk; tile < NTILES; tile += G)
        do_mlp_tile(tile, tid, s_raw, dd, z, r, pos_param, lin0_w, deform_w,
                    deform_b, lin1a_w, lin1b_w, out, counts, aux);

    gbar(bar, G*2);

    // P2: per-image scan + work build + idx scatter
    for (int img = blk; img < BATCH; img += G)
        do_scan_img(img, tid, s_raw, counts, prefix, n_work, work, aux, (int*)recs);

    gbar(bar, G*3);

    // P3: coalesced record fill
    for (int i = gtid; i < BATCH*NPTS; i += NT)
        do_fill_elem(i, z, amp, linamp_w, linamp_b, out, recs);

    gbar(bar, G*4);

    // P4: gather (dual-image atomic writes)
    do_gather(blk*4 + (tid >> 6), G*4, tid & 63, recs, prefix, n_work, work, out);

    // hygiene barrier + self-reset so standalone rocprof replays stay coherent
    gbar(bar, G*5);
    if (blk == 0 && tid == 0)
        __hip_atomic_store(bar, 0, __ATOMIC_RELAXED, __HIP_MEMORY_SCOPE_AGENT);
}

// ================= fallback split kernels (proven structure) =================
__global__ __launch_bounds__(MTPB) void k_mlp(
    const float* __restrict__ z, const float* __restrict__ r,
    const float* __restrict__ pos_param, const float* __restrict__ lin0_w,
    const float* __restrict__ deform_w, const float* __restrict__ deform_b,
    const float* __restrict__ lin1a_w, const float* __restrict__ lin1b_w,
    const int* __restrict__ dflag,
    float* __restrict__ out, int* __restrict__ counts, int* __restrict__ aux)
{
    __shared__ __align__(16) unsigned char s_raw[LDS_BYTES];
    do_mlp_tile(blockIdx.x, threadIdx.x, s_raw, *dflag, z, r, pos_param, lin0_w,
                deform_w, deform_b, lin1a_w, lin1b_w, out, counts, aux);
}

__global__ __launch_bounds__(MTPB) void k_scan(
    const int* __restrict__ counts, int* __restrict__ prefix,
    int* __restrict__ n_work, int* __restrict__ work,
    const int* __restrict__ aux, int* __restrict__ recs_i)
{
    __shared__ __align__(16) unsigned char s_raw[LDS_BYTES];
    do_scan_img(blockIdx.x, threadIdx.x, s_raw, counts, prefix, n_work, work,
                aux, recs_i);
}

__global__ __launch_bounds__(MTPB) void k_fill(
    const float* __restrict__ z, const float* __restrict__ amp,
    const float* __restrict__ linamp_w, const float* __restrict__ linamp_b,
    const float* __restrict__ out, float4* __restrict__ recs)
{
    const int i = blockIdx.x*MTPB + threadIdx.x;
    if (i < BATCH*NPTS) do_fill_elem(i, z, amp, linamp_w, linamp_b, out, recs);
}

__global__ __launch_bounds__(MTPB) void k_gather(
    const float4* __restrict__ recs, const int* __restrict__ prefix,
    const int* __restrict__ n_work, const int* __restrict__ work,
    float* __restrict__ out)
{
    do_gather(blockIdx.x*4 + (threadIdx.x >> 6), gridDim.x*4, threadIdx.x & 63,
              recs, prefix, n_work, work, out);
}

extern "C" void kernel_launch(void* const* d_in, const int* in_sizes, int n_in,
                              void* d_out, int out_size, void* d_ws, size_t ws_size,
                              hipStream_t stream)
{
    const float* z        = (const float*)d_in[0];
    const float* r        = (const float*)d_in[1];
    const float* posp     = (const float*)d_in[2];
    const float* amp      = (const float*)d_in[3];
    const float* lin0_w   = (const float*)d_in[4];
    const float* deform_w = (const float*)d_in[5];
    const float* deform_b = (const float*)d_in[6];
    const float* lin1a_w  = (const float*)d_in[7];
    const float* lin1b_w  = (const float*)d_in[8];
    const float* linamp_w = (const float*)d_in[9];
    const float* linamp_b = (const float*)d_in[10];
    const int*   dflag    = (const int*)d_in[11];
    float* out = (float*)d_out;

    int* ws_i    = (int*)d_ws;
    float4* recs = (float4*)((char*)d_ws + (size_t)WS_INTS*sizeof(int));

    // mode 1 = cooperative mega (validated co-residency), 2 = split fallback
    static int s_mode = 0;
    static int s_G = 0;
    if (s_mode == 0) {
        int dev = 0;
        hipGetDevice(&dev);
        int coop = 0, nCU = 0, bpc = 0;
        hipDeviceGetAttribute(&coop, hipDeviceAttributeCooperativeLaunch, dev);
        hipDeviceGetAttribute(&nCU, hipDeviceAttributeMultiprocessorCount, dev);
        hipError_t oe = hipOccupancyMaxActiveBlocksPerMultiprocessor(&bpc, mega, MTPB, 0);
        if (coop && oe == hipSuccess && bpc >= 1 && nCU > 0) {
            s_G = nCU * bpc;
            s_mode = 1;
        } else {
            s_mode = 2;
        }
        (void)hipGetLastError();
    }

    if (s_mode == 1) {
        hipMemsetAsync(ws_i + BAR_IDX, 0, sizeof(int), stream);   // barrier counter
        int G = s_G;
        void* kargs[] = {
            (void*)&z, (void*)&r, (void*)&posp, (void*)&amp, (void*)&lin0_w,
            (void*)&deform_w, (void*)&deform_b, (void*)&lin1a_w, (void*)&lin1b_w,
            (void*)&linamp_w, (void*)&linamp_b, (void*)&dflag, (void*)&out,
            (void*)&ws_i, (void*)&recs, (void*)&G
        };
        hipError_t le = hipLaunchCooperativeKernel((void*)mega, dim3(G), dim3(MTPB),
                                                   kargs, 0, stream);
        if (le == hipSuccess) return;
        s_mode = 2;                       // cooperative unsupported -> permanent fallback
        (void)hipGetLastError();
    }

    // -------- fallback: proven split pipeline --------
    int* counts = ws_i + WS_COUNTS;
    int* n_work = ws_i + WS_NWORK;
    int* prefix = ws_i + WS_PREFIX;
    int* work   = ws_i + WS_WORK;
    int* aux    = ws_i + WS_AUX;

    hipMemsetAsync(counts, 0, (size_t)BATCH*CELLS*sizeof(int), stream);
    hipMemsetAsync(out, 0, (size_t)2*IMG_ELEMS*sizeof(float), stream);

    k_mlp<<<dim3(NTILES), MTPB, 0, stream>>>(z, r, posp, lin0_w, deform_w, deform_b,
                                             lin1a_w, lin1b_w, dflag, out, counts, aux);
    k_scan<<<dim3(BATCH), MTPB, 0, stream>>>(counts, prefix, n_work, work, aux, (int*)recs);
    k_fill<<<dim3((BATCH*NPTS + MTPB - 1)/MTPB), MTPB, 0, stream>>>(z, amp, linamp_w,
                                                                    linamp_b, out, recs);
    k_gather<<<dim3(2048), MTPB, 0, stream>>>(recs, prefix, n_work, work, out);
}

// Round 12
// 186.925 us; speedup vs baseline: 6.4917x; 6.4917x over previous
//
#include <hip/hip_runtime.h>
#include <math.h>

#define BOX   256
#define NPTS  50000
#define LATD  10
#define NEUR  32
#define NLAY  3
#define BATCH 16

#define MTPB  256
#define MBLKX ((NPTS + MTPB - 1)/MTPB)     // 196 point-tiles per image
#define NTILES (MBLKX*BATCH)               // 3136

#define PTPB  256
#define PBLKX ((NPTS + PTPB - 1)/PTPB)     // 196

#define CELLS_X 64                          // 4x4-px cells
#define CELLS   (CELLS_X*CELLS_X)           // 4096
#define PREF_STRIDE 4104
#define CHUNK   128
#define WCAP    4608

// gather: 2048 blocks x 4 waves = 8192 waves over the GLOBAL chunk list
#define GBLKX   2048

#define IMG_ELEMS (BATCH*BOX*BOX)
#define OFF_IMG2  (IMG_ELEMS)
#define OFF_PROJ  (2*IMG_ELEMS)
#define OFF_POS   (OFF_PROJ + BATCH*NPTS*2)
#define OFF_RES   (OFF_POS  + BATCH*NPTS*3)

// ws ints: counts[16*4096] | n_work[16] | prefix[16*4104] | work[16*4608] | aux[16*50000]
// then (16B aligned): recs float4[16*50000]   -> ~16.8 MB total
#define WS_COUNTS 0
#define WS_NWORK  (BATCH*CELLS)
#define WS_PREFIX (WS_NWORK + BATCH)
#define WS_WORK   (WS_PREFIX + BATCH*PREF_STRIDE)
#define WS_AUX    (WS_WORK + BATCH*WCAP)
#define WS_INTS   (WS_AUX + BATCH*NPTS)

// LDS h-tile row stride in HALFS: 32 cols + pad to 40 (80 B rows, 16B-aligned)
#define HSTRH 40
#define LDS_BYTES (4*64*HSTRH*2 + NEUR*4)   // 20608 B (also fits scan's 16428 B)

typedef _Float16 f16x8 __attribute__((ext_vector_type(8)));
typedef _Float16 f16x4 __attribute__((ext_vector_type(4)));
typedef float    f32x4 __attribute__((ext_vector_type(4)));

#if __has_builtin(__builtin_amdgcn_exp2f)
#define EXP2R(x) __builtin_amdgcn_exp2f(x)
#else
#define EXP2R(x) exp2f(x)
#endif

__device__ __forceinline__ float fast_tanh(float x) {
    return 1.0f - 2.0f / (__expf(2.0f * x) + 1.0f);
}

// ---- kernel A: fused MLP + binning (R6-proven body; NO img zeroing). ----
__global__ __launch_bounds__(MTPB) void k_mlp(
    const float* __restrict__ z, const float* __restrict__ r,
    const float* __restrict__ pos_param, const float* __restrict__ lin0_w,
    const float* __restrict__ deform_w, const float* __restrict__ deform_b,
    const float* __restrict__ lin1a_w, const float* __restrict__ lin1b_w,
    const int* __restrict__ dflag,
    float* __restrict__ out, int* __restrict__ counts, int* __restrict__ aux)
{
    __shared__ __align__(16) unsigned char s_raw[LDS_BYTES];
    _Float16* s_h   = (_Float16*)s_raw;
    float*    s_z   = (float*)(s_raw + 4*64*HSTRH*2);
    int*      s_cnt = (int*)s_raw;          // aliases tiles; used post-reads only

    const int tile  = blockIdx.x;
    const int tid   = threadIdx.x;
    const int wave  = tid >> 6;
    const int lane  = tid & 63;
    const int cfrag = lane & 15;            // A row / B col / D col
    const int rq    = lane >> 4;
    const int k0    = rq * 8;
    _Float16* __restrict__ s_hw = s_h + wave*64*HSTRH;

    const int b  = tile / MBLKX;
    const int tx = tile - b*MBLKX;
    const int dd = *dflag;

    if (tid < NEUR) {
        float acc = 0.f;
        #pragma unroll
        for (int j = 0; j < LATD-1; j++)
            acc = fmaf(lin0_w[tid*12 + 3 + j], z[b*LATD + j], acc);
        s_z[tid] = acc;
    }
    __syncthreads();

    const int n  = tx*MTPB + tid;
    const bool v0 = (n < NPTS);
    const int m0 = v0 ? n : (NPTS-1);

    const float p0w = pos_param[m0*3+0], p1w = pos_param[m0*3+1], p2w = pos_param[m0*3+2];
    float res0 = 0.f, res1 = 0.f, res2 = 0.f;

    if (dd > 0) {
        f16x8 bfrag[NLAY][2];
        float bias_c[NLAY][2];
        #pragma unroll
        for (int l = 0; l < NLAY; ++l) {
            #pragma unroll
            for (int nt = 0; nt < 2; ++nt) {
                const int c = cfrag + 16*nt;
                const float* wp = deform_w + l*NEUR*NEUR + c*NEUR + k0;
                const f32x4 w0 = *(const f32x4*)wp;
                const f32x4 w1 = *(const f32x4*)(wp + 4);
                f16x8 bv;
                bv[0]=(_Float16)w0[0]; bv[1]=(_Float16)w0[1];
                bv[2]=(_Float16)w0[2]; bv[3]=(_Float16)w0[3];
                bv[4]=(_Float16)w1[0]; bv[5]=(_Float16)w1[1];
                bv[6]=(_Float16)w1[2]; bv[7]=(_Float16)w1[3];
                bfrag[l][nt]  = bv;
                bias_c[l][nt] = deform_b[l*NEUR + c];
            }
        }

        #pragma unroll
        for (int o4 = 0; o4 < 8; ++o4) {
            f16x4 h4;
            #pragma unroll
            for (int jj = 0; jj < 4; ++jj) {
                const int o = o4*4 + jj;
                h4[jj] = (_Float16)fmaf(lin0_w[o*12+0], p0w,
                                   fmaf(lin0_w[o*12+1], p1w,
                                   fmaf(lin0_w[o*12+2], p2w, s_z[o])));
            }
            *(f16x4*)&s_hw[lane*HSTRH + o4*4] = h4;
        }
        __syncthreads();

        float rs0[4][4], rs1[4][4];
        #pragma unroll
        for (int mt = 0; mt < 4; ++mt) {
            #pragma unroll
            for (int rr = 0; rr < 4; ++rr) {
                const int row = 16*mt + 4*rq + rr;
                rs0[mt][rr] = (float)s_hw[row*HSTRH + cfrag];
                rs1[mt][rr] = (float)s_hw[row*HSTRH + cfrag + 16];
            }
        }

        const f32x4 zc = {0.f, 0.f, 0.f, 0.f};
        #pragma unroll
        for (int l = 0; l < NLAY; ++l) {
            f16x8 af[4];
            #pragma unroll
            for (int mt = 0; mt < 4; ++mt)
                af[mt] = *(const f16x8*)&s_hw[(16*mt + cfrag)*HSTRH + k0];
            f32x4 ac0[4], ac1[4];
            #pragma unroll
            for (int mt = 0; mt < 4; ++mt) {
                ac0[mt] = __builtin_amdgcn_mfma_f32_16x16x32_f16(af[mt], bfrag[l][0], zc, 0, 0, 0);
                ac1[mt] = __builtin_amdgcn_mfma_f32_16x16x32_f16(af[mt], bfrag[l][1], zc, 0, 0, 0);
            }
            __syncthreads();
            const float b0l = bias_c[l][0], b1l = bias_c[l][1];
            #pragma unroll
            for (int mt = 0; mt < 4; ++mt) {
                #pragma unroll
                for (int rr = 0; rr < 4; ++rr) {
                    const int row = 16*mt + 4*rq + rr;
                    const float h0n = fmaxf(ac0[mt][rr] + b0l, 0.f) + rs0[mt][rr];
                    const float h1n = fmaxf(ac1[mt][rr] + b1l, 0.f) + rs1[mt][rr];
                    rs0[mt][rr] = h0n;
                    rs1[mt][rr] = h1n;
                    s_hw[row*HSTRH + cfrag]      = (_Float16)h0n;
                    s_hw[row*HSTRH + cfrag + 16] = (_Float16)h1n;
                }
            }
            __syncthreads();
        }

        float t0 = 0.f, t1 = 0.f, t2 = 0.f;
        #pragma unroll
        for (int ch = 0; ch < 4; ++ch) {
            const f16x8 hv = *(const f16x8*)&s_hw[lane*HSTRH + ch*8];
            #pragma unroll
            for (int jj = 0; jj < 8; ++jj) {
                const int j = ch*8 + jj;
                const float hf = (float)hv[jj];
                t0 = fmaf(lin1a_w[0*NEUR + j], hf, t0);
                t1 = fmaf(lin1a_w[1*NEUR + j], hf, t1);
                t2 = fmaf(lin1a_w[2*NEUR + j], hf, t2);
            }
        }
        t0 = fast_tanh(t0); t1 = fast_tanh(t1); t2 = fast_tanh(t2);
        res0 = fmaf(t0, lin1b_w[0], fmaf(t1, lin1b_w[1], t2*lin1b_w[2]));
        res1 = fmaf(t0, lin1b_w[3], fmaf(t1, lin1b_w[4], t2*lin1b_w[5]));
        res2 = fmaf(t0, lin1b_w[6], fmaf(t1, lin1b_w[7], t2*lin1b_w[8]));
    }

    const float r00 = r[b*9+0], r01 = r[b*9+1];
    const float r10 = r[b*9+3], r11 = r[b*9+4];
    const float r20 = r[b*9+6], r21 = r[b*9+7];

    int cell = 0;
    if (v0) {
        const float pos0 = p0w + res0, pos1 = p1w + res1, pos2 = p2w + res2;
        const float pj0 = fmaf(pos0, r00, fmaf(pos1, r10, pos2*r20));
        const float pj1 = fmaf(pos0, r01, fmaf(pos1, r11, pos2*r21));
        const long long bn = (long long)b*NPTS + n;
        out[OFF_PROJ + bn*2 + 0] = pj0;  out[OFF_PROJ + bn*2 + 1] = pj1;
        out[OFF_POS  + bn*3 + 0] = pos0; out[OFF_POS  + bn*3 + 1] = pos1;
        out[OFF_POS  + bn*3 + 2] = pos2;
        out[OFF_RES  + bn*3 + 0] = res0; out[OFF_RES + bn*3 + 1] = res1;
        out[OFF_RES  + bn*3 + 2] = res2;
        const float px0 = (pj0 + 0.5f) * (float)(BOX-1);
        const float px1 = (pj1 + 0.5f) * (float)(BOX-1);
        const int c0 = (int)fminf(fmaxf(floorf(px0 + 0.5f), 0.f), 255.f);
        const int c1 = (int)fminf(fmaxf(floorf(px1 + 0.5f), 0.f), 255.f);
        cell = (c0>>2)*CELLS_X + (c1>>2);
    }

    __syncthreads();                        // all tile reads done -> reuse as s_cnt
    for (int i = tid; i < CELLS; i += MTPB) s_cnt[i] = 0;
    __syncthreads();
    int rank = 0;
    if (v0) rank = atomicAdd(&s_cnt[cell], 1);
    __syncthreads();
    for (int c = tid; c < CELLS; c += MTPB) {
        const int cnt = s_cnt[c];
        if (cnt > 0) s_cnt[c] = atomicAdd(&counts[b*CELLS + c], cnt);
    }
    __syncthreads();
    if (v0) aux[b*NPTS + n] = (cell << 16) | (s_cnt[cell] + rank);
}

// ---- kernel B: per-image scan (256 thr, 16 cells/thr, shuffle) + work build ----
__global__ __launch_bounds__(MTPB) void k_scan(
    const int* __restrict__ counts, int* __restrict__ prefix,
    int* __restrict__ n_work, int* __restrict__ work)
{
    __shared__ int swsum[4];
    __shared__ int snw;
    const int img = blockIdx.x, tid = threadIdx.x;
    const int lane = tid & 63, wid = tid >> 6;
    if (tid == 0) snw = 0;

    int c[16];
    const int4* cp = (const int4*)(counts + img*CELLS) + tid*4;
    #pragma unroll
    for (int q = 0; q < 4; ++q) {
        const int4 v = cp[q];
        c[q*4+0]=v.x; c[q*4+1]=v.y; c[q*4+2]=v.z; c[q*4+3]=v.w;
    }
    int pres[16]; int run = 0;
    #pragma unroll
    for (int i = 0; i < 16; ++i) { pres[i] = run; run += c[i]; }

    int sc = run;
    #pragma unroll
    for (int off = 1; off < 64; off <<= 1) {
        const int u = __shfl_up(sc, off, 64);
        if (lane >= off) sc += u;
    }
    if (lane == 63) swsum[wid] = sc;
    __syncthreads();
    int woff = 0;
    #pragma unroll
    for (int w = 0; w < 3; ++w) if (w < wid) woff += swsum[w];
    const int base = woff + sc - run;

    int* gpre = prefix + img*PREF_STRIDE;
    #pragma unroll
    for (int i = 0; i < 16; ++i) gpre[tid*16 + i] = base + pres[i];
    if (tid == 255) gpre[CELLS] = woff + sc;

    // work item = (cell << 9) | chunk_idx  (chunk_idx < 512, CHUNK=128)
    #pragma unroll
    for (int i = 0; i < 16; ++i) {
        const int cnt = c[i];
        if (cnt > 0) {
            const int cell = tid*16 + i;
            const int nch = (cnt + CHUNK - 1) >> 7;
            const int wb = atomicAdd(&snw, nch);
            for (int k = 0; k < nch; ++k) work[img*WCAP + wb + k] = (cell << 9) | k;
        }
    }
    __syncthreads();
    if (tid == 0) n_work[img] = snw;
}

// ---- kernel C: place records at cell-sorted positions (16B scatter is fine — R9) ----
__global__ __launch_bounds__(PTPB) void k_place(
    const float* __restrict__ z, const float* __restrict__ amp,
    const float* __restrict__ linamp_w, const float* __restrict__ linamp_b,
    const float* __restrict__ out, const int* __restrict__ prefix,
    const int* __restrict__ aux, float4* __restrict__ recs)
{
    const int b = blockIdx.y;
    const int n = blockIdx.x*PTPB + threadIdx.x;
    if (n >= NPTS) return;

    const long long bn = (long long)b*NPTS + n;
    const float pj0 = out[OFF_PROJ + bn*2 + 0];
    const float pj1 = out[OFF_PROJ + bn*2 + 1];
    const float lo = fmaf(z[b*LATD + LATD-1], linamp_w[n], linamp_b[n]);
    const float a  = amp[0] / (1.0f + __expf(-lo));
    const float px0 = (pj0 + 0.5f) * (float)(BOX-1);
    const float px1 = (pj1 + 0.5f) * (float)(BOX-1);

    const int av  = aux[b*NPTS + n];
    const int cell = av >> 16, wr = av & 0xFFFF;
    const int dst  = prefix[b*PREF_STRIDE + cell] + wr;
    // rec = (row, col, amp, center-row)
    recs[(long long)b*NPTS + dst] = make_float4(px0, px1, a, floorf(px0 + 0.5f));
}

// ---- kernel D: gather over the GLOBAL chunk list (all images jointly);
//      dual-writes both output image copies (replaces the copy kernel). ----
__global__ __launch_bounds__(MTPB) void k_gather(
    const float4* __restrict__ recs, const int* __restrict__ prefix,
    const int* __restrict__ n_work, const int* __restrict__ work,
    float* __restrict__ out)
{
    const int lane = threadIdx.x & 63;
    const int gw = blockIdx.x*4 + (threadIdx.x >> 6);
    const int GW = gridDim.x*4;
    const float Kc  = -0.32059884f;            // -log2(e)/(2*sig^2)
    const float K8  = 8.0f  * Kc;
    const float K16 = 16.0f * Kc;
    const float C32 = 0.00081582472f;          // 2^(32*Kc)

    // prefix over n_work[0..15]; all indices static (rule #20: no scratch)
    int nwoff[BATCH+1];
    nwoff[0] = 0;
    #pragma unroll
    for (int q = 0; q < BATCH; ++q) nwoff[q+1] = nwoff[q] + n_work[q];
    const int total = nwoff[BATCH];

    for (int g = gw; g < total; g += GW) {
        int b = 0, base = 0;
        #pragma unroll
        for (int q = 0; q < BATCH; ++q) {
            const bool geq = (g >= nwoff[q+1]);
            b    = geq ? q+1        : b;
            base = geq ? nwoff[q+1] : base;
        }
        const int it = g - base;

        const int* __restrict__ P = prefix + b*PREF_STRIDE;
        const float4* __restrict__ R = recs + (long long)b*NPTS;
        float* __restrict__ img  = out + (size_t)b*BOX*BOX;
        float* __restrict__ img2 = out + OFF_IMG2 + (size_t)b*BOX*BOX;

        const int wd   = __builtin_amdgcn_readfirstlane(work[b*WCAP + it]);
        const int cell = wd >> 9, kch = wd & 511;
        const int s = P[cell] + kch*CHUNK;          // scalar (cell uniform)
        const int e = min(P[cell+1], s + CHUNK);

        const int cy = cell >> 6, cx = cell & 63;
        const int col = lane & 15, r0 = lane >> 4;
        const int gx  = 4*cx - 4 + col;
        const int gy0 = 4*cy - 4 + r0;
        const float xf  = (float)gx;
        const float y0f = (float)gy0;
        const float frc = (float)(r0 + 4*cy);

        float a0 = 0.f, a1 = 0.f, a2 = 0.f;
        #pragma unroll 8
        for (int rr = s; rr < e; ++rr) {
            const float4 rc = R[rr];                // uniform addr -> s_load_dwordx4
            const float ry = rc.x, rx = rc.y, ra = rc.z, stf = rc.w;
            const float dx = xf - rx;
            const float dy = y0f - ry;
            const float d2 = fmaf(dy, dy, dx*dx);
            float gv = ra * EXP2R(d2 * Kc);
            gv = (fabsf(dx) <= 4.5f) ? gv : 0.f;
            const float u  = EXP2R(fminf(fmaf(dy, K8, K16), 60.f));
            const float uu = (u * u) * C32;
            const float g0m = (frc >= stf) ? gv : 0.f;
            const float u2m = (frc <= stf) ? uu : 0.f;
            a0 += g0m;
            a1 = fmaf(gv, u,   a1);
            a2 = fmaf(gv, u2m, a2);
        }

        if (gx >= 0 && gx < BOX) {
            if (a0 != 0.f && gy0 >= 0) {
                atomicAdd(&img [ gy0     *BOX + gx], a0);
                atomicAdd(&img2[ gy0     *BOX + gx], a0);
            }
            if (a1 != 0.f) {
                atomicAdd(&img [(gy0 + 4)*BOX + gx], a1);
                atomicAdd(&img2[(gy0 + 4)*BOX + gx], a1);
            }
            if (a2 != 0.f && gy0 + 8 < BOX) {
                atomicAdd(&img [(gy0 + 8)*BOX + gx], a2);
                atomicAdd(&img2[(gy0 + 8)*BOX + gx], a2);
            }
        }
    }
}

extern "C" void kernel_launch(void* const* d_in, const int* in_sizes, int n_in,
                              void* d_out, int out_size, void* d_ws, size_t ws_size,
                              hipStream_t stream)
{
    const float* z        = (const float*)d_in[0];
    const float* r        = (const float*)d_in[1];
    const float* posp     = (const float*)d_in[2];
    const float* amp      = (const float*)d_in[3];
    const float* lin0_w   = (const float*)d_in[4];
    const float* deform_w = (const float*)d_in[5];
    const float* deform_b = (const float*)d_in[6];
    const float* lin1a_w  = (const float*)d_in[7];
    const float* lin1b_w  = (const float*)d_in[8];
    const float* linamp_w = (const float*)d_in[9];
    const float* linamp_b = (const float*)d_in[10];
    const int*   dflag    = (const int*)d_in[11];
    float* out = (float*)d_out;

    int* ws_i    = (int*)d_ws;
    int* counts  = ws_i + WS_COUNTS;
    int* n_work  = ws_i + WS_NWORK;
    int* prefix  = ws_i + WS_PREFIX;
    int* work    = ws_i + WS_WORK;
    int* aux     = ws_i + WS_AUX;
    float4* recs = (float4*)((char*)d_ws + (size_t)WS_INTS*sizeof(int));

    hipMemsetAsync(counts, 0, (size_t)BATCH*CELLS*sizeof(int), stream);
    hipMemsetAsync(out, 0, (size_t)2*IMG_ELEMS*sizeof(float), stream);

    k_mlp<<<dim3(NTILES), MTPB, 0, stream>>>(z, r, posp, lin0_w, deform_w, deform_b,
                                             lin1a_w, lin1b_w, dflag, out, counts, aux);

    k_scan<<<dim3(BATCH), MTPB, 0, stream>>>(counts, prefix, n_work, work);

    dim3 gridP(PBLKX, BATCH);
    k_place<<<gridP, PTPB, 0, stream>>>(z, amp, linamp_w, linamp_b, out, prefix, aux, recs);

    k_gather<<<dim3(GBLKX), MTPB, 0, stream>>>(recs, prefix, n_work, work, out);
}